// Round 3
// baseline (303.164 us; speedup 1.0000x reference)
//
#include <hip/hip_runtime.h>

#define TT 4096
#define BLK 256
#define PER 16   // TT / BLK
#define EPSV 1e-8f

__global__ void zero_out_kernel(float* out) { out[0] = 0.0f; }

__global__ __launch_bounds__(BLK) void w2_loss_kernel(
    const float* __restrict__ traces,
    const float* __restrict__ q_raw,
    float* __restrict__ out) {
  __shared__ float wave_sums[4];
  __shared__ float wave_red[4];

  const int tid = threadIdx.x;
  const long trace = blockIdx.x;
  const float* __restrict__ tr = traces + trace * TT;
  const float* __restrict__ qr = q_raw + trace * TT;

  const int base = tid * PER;

  // ---- traces loads (feed the scan critical path), coalesced float4 ----
  float4 trv[4];
  {
    const float4* tr4 = (const float4*)(tr + base);
#pragma unroll
    for (int j = 0; j < 4; ++j) trv[j] = tr4[j];
  }
  float nb = (base + PER < TT) ? tr[base + PER] : 0.0f;

  // s[i] = traces[i]^2 + eps for own 16 elements + right neighbor.
  float s[PER + 1];
#pragma unroll
  for (int j = 0; j < 4; ++j) {
    s[4 * j + 0] = trv[j].x * trv[j].x + EPSV;
    s[4 * j + 1] = trv[j].y * trv[j].y + EPSV;
    s[4 * j + 2] = trv[j].z * trv[j].z + EPSV;
    s[4 * j + 3] = trv[j].w * trv[j].w + EPSV;
  }
  s[PER] = (base + PER < TT) ? (nb * nb + EPSV) : 0.0f;

  // t[i] = (float)i * 1e-3f  — bit-exact vs arange(T)*1e-3 in fp32.
  // Local trapezoid increments (unnormalized pdf) and local cumsum.
  float lc[PER + 1];
  lc[0] = 0.0f;
#pragma unroll
  for (int m = 0; m < PER; ++m) {
    float t0 = (float)(base + m) * 1e-3f;
    float t1 = (float)(base + m + 1) * 1e-3f;
    float incr = (base + m < TT - 1) ? 0.5f * (s[m] + s[m + 1]) * (t1 - t0)
                                     : 0.0f;
    lc[m + 1] = lc[m] + incr;
  }
  const float tot = lc[PER];

  // Wave-level inclusive scan of thread totals (wave = 64 lanes).
  float v = tot;
#pragma unroll
  for (int off = 1; off < 64; off <<= 1) {
    float n = __shfl_up(v, off, 64);
    if ((tid & 63) >= off) v += n;
  }
  if ((tid & 63) == 63) wave_sums[tid >> 6] = v;
  __syncthreads();  // only gates the 16B wave_sums exchange now

  const int wv = tid >> 6;
  float wave_off = 0.0f;
  if (wv > 0) wave_off += wave_sums[0];
  if (wv > 1) wave_off += wave_sums[1];
  if (wv > 2) wave_off += wave_sums[2];
  const float excl = (v - tot) + wave_off;  // exclusive prefix of this thread
  const float norm = wave_sums[0] + wave_sums[1] + wave_sums[2] + wave_sums[3];
  const float inv_norm = 1.0f / norm;

  // Precompute all gather indices/fractions, then issue all 32 global loads
  // (q table is 16KB -> L1-resident; lanes' indices are sorted -> few lines).
  int idx[PER];
  float frac[PER];
#pragma unroll
  for (int m = 0; m < PER; ++m) {
    float x = (excl + lc[m]) * inv_norm;       // cdf in [0,1]
    float u = x * (float)(TT - 1);             // analytic index on uniform p
    int i0 = (int)floorf(u);
    i0 = (i0 < 0) ? 0 : ((i0 > TT - 2) ? TT - 2 : i0);
    float f = u - (float)i0;
    idx[m] = i0;
    frac[m] = fminf(fmaxf(f, 0.0f), 1.0f);     // jnp.interp endpoint clamp
  }
  float q0v[PER], q1v[PER];
#pragma unroll
  for (int m = 0; m < PER; ++m) {
    q0v[m] = qr[idx[m]];
    q1v[m] = qr[idx[m] + 1];
  }

  float local = 0.0f;
#pragma unroll
  for (int m = 0; m < PER; ++m) {
    float transport = q0v[m] + frac[m] * (q1v[m] - q0v[m]);
    float tm = (float)(base + m) * 1e-3f;
    float d = tm - transport;
    float tlo = (float)((base + m == 0) ? 0 : (base + m - 1)) * 1e-3f;
    float thi = (float)((base + m == TT - 1) ? (TT - 1) : (base + m + 1)) * 1e-3f;
    float w = 0.5f * (thi - tlo);              // collapsed trapz weight
    local += d * d * s[m] * w;
  }
  local *= inv_norm;

  // Block reduce, then one atomic per block.
#pragma unroll
  for (int off = 32; off > 0; off >>= 1) local += __shfl_down(local, off, 64);
  if ((tid & 63) == 0) wave_red[tid >> 6] = local;
  __syncthreads();
  if (tid == 0) {
    float blk = wave_red[0] + wave_red[1] + wave_red[2] + wave_red[3];
    atomicAdd(out, blk);
  }
}

extern "C" void kernel_launch(void* const* d_in, const int* in_sizes, int n_in,
                              void* d_out, int out_size, void* d_ws, size_t ws_size,
                              hipStream_t stream) {
  const float* traces = (const float*)d_in[0];
  const float* q_raw  = (const float*)d_in[3];
  float* out = (float*)d_out;

  zero_out_kernel<<<1, 1, 0, stream>>>(out);

  const int n_traces = in_sizes[0] / TT;  // B*R = 8192
  w2_loss_kernel<<<n_traces, BLK, 0, stream>>>(traces, q_raw, out);
}

// Round 4
// 284.077 us; speedup vs baseline: 1.0672x; 1.0672x over previous
//
#include <hip/hip_runtime.h>

#define TT 4096
#define BLK 256
#define PER 16   // TT / BLK
#define EPSV 1e-8f

__global__ __launch_bounds__(BLK) void w2_loss_kernel(
    const float* __restrict__ traces,
    const float* __restrict__ q_raw,
    float* __restrict__ part) {
  __shared__ float lds_q[TT];
  __shared__ float wave_sums[4];
  __shared__ float wave_red[4];

  const int tid = threadIdx.x;
  const long trace = blockIdx.x;
  const float* __restrict__ tr = traces + trace * TT;
  const float* __restrict__ qr = q_raw + trace * TT;

  const int base = tid * PER;

  // ---- traces loads FIRST (they feed the scan critical path) ----
  float4 trv[4];
  {
    const float4* tr4 = (const float4*)(tr + base);
#pragma unroll
    for (int j = 0; j < 4; ++j) trv[j] = tr4[j];
  }
  float nb = (base + PER < TT) ? tr[base + PER] : 0.0f;

  // ---- stage q_raw into LDS, coalesced float4 ----
  {
    const float4* q4 = (const float4*)qr;
    float4* lq4 = (float4*)lds_q;
#pragma unroll
    for (int j = 0; j < 4; ++j) lq4[tid + BLK * j] = q4[tid + BLK * j];
  }

  // s[i] = traces[i]^2 + eps for own 16 elements + right neighbor.
  float s[PER + 1];
#pragma unroll
  for (int j = 0; j < 4; ++j) {
    s[4 * j + 0] = trv[j].x * trv[j].x + EPSV;
    s[4 * j + 1] = trv[j].y * trv[j].y + EPSV;
    s[4 * j + 2] = trv[j].z * trv[j].z + EPSV;
    s[4 * j + 3] = trv[j].w * trv[j].w + EPSV;
  }
  s[PER] = (base + PER < TT) ? (nb * nb + EPSV) : 0.0f;

  // t[i] = (float)i * 1e-3f  — bit-exact vs arange(T)*1e-3 in fp32.
  float lc[PER + 1];
  lc[0] = 0.0f;
#pragma unroll
  for (int m = 0; m < PER; ++m) {
    float t0 = (float)(base + m) * 1e-3f;
    float t1 = (float)(base + m + 1) * 1e-3f;
    float incr = (base + m < TT - 1) ? 0.5f * (s[m] + s[m + 1]) * (t1 - t0)
                                     : 0.0f;
    lc[m + 1] = lc[m] + incr;
  }
  const float tot = lc[PER];

  // Wave-level inclusive scan of thread totals (wave = 64 lanes).
  float v = tot;
#pragma unroll
  for (int off = 1; off < 64; off <<= 1) {
    float n = __shfl_up(v, off, 64);
    if ((tid & 63) >= off) v += n;
  }
  if ((tid & 63) == 63) wave_sums[tid >> 6] = v;
  __syncthreads();  // covers wave_sums AND lds_q staging

  const int wv = tid >> 6;
  float wave_off = 0.0f;
  if (wv > 0) wave_off += wave_sums[0];
  if (wv > 1) wave_off += wave_sums[1];
  if (wv > 2) wave_off += wave_sums[2];
  const float excl = (v - tot) + wave_off;
  const float norm = wave_sums[0] + wave_sums[1] + wave_sums[2] + wave_sums[3];
  const float inv_norm = 1.0f / norm;

  // Main per-element loop: cdf -> interp on analytic uniform p -> loss.
  float local = 0.0f;
#pragma unroll
  for (int m = 0; m < PER; ++m) {
    float x = (excl + lc[m]) * inv_norm;       // cdf in [0,1]
    float u = x * (float)(TT - 1);             // analytic index on uniform p
    int i0 = (int)floorf(u);
    i0 = (i0 < 0) ? 0 : ((i0 > TT - 2) ? TT - 2 : i0);
    float f = u - (float)i0;
    f = fminf(fmaxf(f, 0.0f), 1.0f);           // jnp.interp endpoint clamp
    float q0 = lds_q[i0];
    float q1 = lds_q[i0 + 1];
    float transport = q0 + f * (q1 - q0);
    float tm = (float)(base + m) * 1e-3f;
    float d = tm - transport;
    float tlo = (float)((base + m == 0) ? 0 : (base + m - 1)) * 1e-3f;
    float thi = (float)((base + m == TT - 1) ? (TT - 1) : (base + m + 1)) * 1e-3f;
    float w = 0.5f * (thi - tlo);              // collapsed trapz weight
    local += d * d * s[m] * w;
  }
  local *= inv_norm;

  // Block reduce, then ONE COALESCED STORE per block (no same-address atomic).
#pragma unroll
  for (int off = 32; off > 0; off >>= 1) local += __shfl_down(local, off, 64);
  if ((tid & 63) == 0) wave_red[tid >> 6] = local;
  __syncthreads();
  if (tid == 0) {
    part[blockIdx.x] = wave_red[0] + wave_red[1] + wave_red[2] + wave_red[3];
  }
}

__global__ __launch_bounds__(BLK) void reduce_kernel(
    const float* __restrict__ part, float* __restrict__ out, int n) {
  __shared__ float wave_red[4];
  const int tid = threadIdx.x;
  float local = 0.0f;
  for (int i = tid; i < n; i += BLK) local += part[i];
#pragma unroll
  for (int off = 32; off > 0; off >>= 1) local += __shfl_down(local, off, 64);
  if ((tid & 63) == 0) wave_red[tid >> 6] = local;
  __syncthreads();
  if (tid == 0) out[0] = wave_red[0] + wave_red[1] + wave_red[2] + wave_red[3];
}

extern "C" void kernel_launch(void* const* d_in, const int* in_sizes, int n_in,
                              void* d_out, int out_size, void* d_ws, size_t ws_size,
                              hipStream_t stream) {
  const float* traces = (const float*)d_in[0];
  const float* q_raw  = (const float*)d_in[3];
  float* out = (float*)d_out;
  float* part = (float*)d_ws;  // 8192 floats = 32 KB scratch

  const int n_traces = in_sizes[0] / TT;  // B*R = 8192
  w2_loss_kernel<<<n_traces, BLK, 0, stream>>>(traces, q_raw, part);
  reduce_kernel<<<1, BLK, 0, stream>>>(part, out, n_traces);
}